// Round 1
// baseline (242.829 us; speedup 1.0000x reference)
//
#include <hip/hip_runtime.h>

// ---------------------------------------------------------------------------
// PairInteractionGrid: B=4,T=64,N=32,M=32,D=128
//   p = price@W_p + b_p ; v = liquid@W_v + b_v
//   z = p@W1a + v@W1b + (p*v)@W1c + |p-v|@W1d + b1   (W1 split in 4 K-blocks)
//   out = silu(z)@W2 + b2
// Decomposition: pA = price@(W_p@W1a)+c1 per n-row, vB = liquid@(W_v@W1b) per
// m-row -> only the pair-dependent GEMMs ((p*v)@W1c, |p-v|@W1d, h@W2) run per
// pair. All matmuls bf16 MFMA, fp32 accumulate.
// ---------------------------------------------------------------------------

typedef short  short8  __attribute__((ext_vector_type(8)));
typedef float  f32x4   __attribute__((ext_vector_type(4)));
typedef float  f32x16  __attribute__((ext_vector_type(16)));

#define DEV static __device__ __forceinline__

DEV float bf2f(unsigned short h) {
  unsigned u = ((unsigned)h) << 16;
  float f;
  __builtin_memcpy(&f, &u, 4);
  return f;
}
DEV unsigned short f2bf(float f) {   // round-nearest-even
  unsigned u;
  __builtin_memcpy(&u, &f, 4);
  unsigned r = (u + 0x7FFFu + ((u >> 16) & 1u)) >> 16;
  return (unsigned short)r;
}

// ---------------------------------------------------------------------------
// k0: weight folding + fragment-order swizzles (tiny)
//  w1cd : [W1c;W1d] K=256 in 32x32x16 B-frag order: ((kt*4+ct)*64+lane)*8+j,
//         k=kt*16+(lane>>5)*8+j, c=ct*32+(lane&31). val=W1[256+k][c] (both halves!)
//  w2sw/wpsw/gpsw/wvsw/gvsw : 16x16x32 B-frag order: ((ct*4+kt)*64+lane)*8+j,
//         k=kt*32+((lane>>4)&3)*8+j, n=ct*16+(lane&15)
//  c1   : b_p@W1a + b_v@W1b + b1 (fp32)
// ---------------------------------------------------------------------------
__global__ void k0_prep(const float* __restrict__ Wp, const float* __restrict__ bp,
                        const float* __restrict__ Wv, const float* __restrict__ bv,
                        const float* __restrict__ W1, const float* __restrict__ b1,
                        const float* __restrict__ W2,
                        unsigned short* __restrict__ w1cd, unsigned short* __restrict__ w2sw,
                        unsigned short* __restrict__ wpsw, unsigned short* __restrict__ gpsw,
                        unsigned short* __restrict__ wvsw, unsigned short* __restrict__ gvsw,
                        float* __restrict__ c1) {
  int t = blockIdx.x * 256 + threadIdx.x;
  if (t < 32768) {                       // w1cd
    int j = t & 7, lane = (t >> 3) & 63, r2 = t >> 9;
    int ct = r2 & 3, kt = r2 >> 2;
    int k = kt * 16 + (lane >> 5) * 8 + j;
    int c = ct * 32 + (lane & 31);
    w1cd[t] = f2bf(W1[(256 + k) * 128 + c]);     // k<128 -> W1c row 256+k; k>=128 -> W1d row 384+(k-128)=256+k
  } else if (t < 114688) {               // 16x16x32-frag sections
    int e = t - 32768;
    int sec = e >> 14;                   // 0:w2 1:wp 2:gp 3:wv 4:gv
    int f = e & 16383;
    int j = f & 7, lane = (f >> 3) & 63, r2 = f >> 9;
    int kt = r2 & 3, ct = r2 >> 2;
    int k = kt * 32 + ((lane >> 4) & 3) * 8 + j;
    int n = ct * 16 + (lane & 15);
    if (sec == 0) {
      w2sw[f] = f2bf(W2[k * 128 + n]);
    } else if (sec == 1) {
      wpsw[f] = f2bf(Wp[k * 128 + n]);
    } else if (sec == 2) {
      float s = 0.f;
      for (int e2 = 0; e2 < 128; e2++) s += Wp[k * 128 + e2] * W1[e2 * 128 + n];
      gpsw[f] = f2bf(s);
    } else if (sec == 3) {
      wvsw[f] = f2bf(Wv[k * 128 + n]);
    } else {
      float s = 0.f;
      for (int e2 = 0; e2 < 128; e2++) s += Wv[k * 128 + e2] * W1[(128 + e2) * 128 + n];
      gvsw[f] = f2bf(s);
    }
  } else if (t < 114816) {               // c1
    int c = t - 114688;
    float s = b1[c];
    for (int e2 = 0; e2 < 128; e2++)
      s += bp[e2] * W1[e2 * 128 + c] + bv[e2] * W1[(128 + e2) * 128 + c];
    c1[c] = s;
  }
}

// ---------------------------------------------------------------------------
// k1: projection GEMM. grid=256: b>>2 = 128-row chunk, b&3 = {side,half}
//  side0/half0: p_bf  = bf16(price@Wp + b_p)          [row][128]
//  side0/half1: pAc   = price@Gp + c1 (fp32)          [row][128]
//  side1/half0: v_bf  = bf16(liquid@Wv + b_v)         [row][128]
//  side1/half1: vbsw  = bf16(liquid@Gv) in 32x32x16 B-frag order per bt (K=32)
// ---------------------------------------------------------------------------
__global__ __launch_bounds__(256, 2) void k1_proj(
    const float* __restrict__ price, const float* __restrict__ liquid,
    const float* __restrict__ bp, const float* __restrict__ bv, const float* __restrict__ c1,
    const unsigned short* __restrict__ wpsw, const unsigned short* __restrict__ gpsw,
    const unsigned short* __restrict__ wvsw, const unsigned short* __restrict__ gvsw,
    unsigned short* __restrict__ pbf, unsigned short* __restrict__ vbf,
    float* __restrict__ pAc, unsigned short* __restrict__ vbsw) {
  __shared__ __align__(16) unsigned short sA[128 * 136];
  int b = blockIdx.x;
  int chunk = b >> 2, sel = b & 3;
  int side = sel >> 1, half = sel & 1;
  int rowbase = chunk * 128;
  const float* src = side ? liquid : price;
  const unsigned short* bsw = side ? (half ? gvsw : wvsw) : (half ? gpsw : wpsw);
  int tid = threadIdx.x;

  // stage A tile (128x128 fp32 -> bf16, padded stride 136)
#pragma unroll
  for (int i = 0; i < 16; i++) {
    int e4 = i * 256 + tid;
    int row = e4 >> 5, c4 = (e4 & 31) * 4;
    float4 f = *(const float4*)(src + (rowbase + row) * 128 + c4);
    unsigned u0 = (unsigned)f2bf(f.x) | ((unsigned)f2bf(f.y) << 16);
    unsigned u1 = (unsigned)f2bf(f.z) | ((unsigned)f2bf(f.w) << 16);
    uint2 pk; pk.x = u0; pk.y = u1;
    *(uint2*)&sA[row * 136 + c4] = pk;
  }
  __syncthreads();

  int lane = tid & 63, w = tid >> 6;
  int l15 = lane & 15, q4 = lane >> 4;
  f32x4 acc[2][8] = {};
#pragma unroll
  for (int kt = 0; kt < 4; kt++) {
    short8 a0 = *(const short8*)&sA[(w * 32 + l15) * 136 + kt * 32 + q4 * 8];
    short8 a1 = *(const short8*)&sA[(w * 32 + 16 + l15) * 136 + kt * 32 + q4 * 8];
#pragma unroll
    for (int ct = 0; ct < 8; ct++) {
      short8 bfr = *(const short8*)(bsw + ((ct * 4 + kt) * 64 + lane) * 8);
      acc[0][ct] = __builtin_amdgcn_mfma_f32_16x16x32_bf16(a0, bfr, acc[0][ct], 0, 0, 0);
      acc[1][ct] = __builtin_amdgcn_mfma_f32_16x16x32_bf16(a1, bfr, acc[1][ct], 0, 0, 0);
    }
  }

#pragma unroll
  for (int rg = 0; rg < 2; rg++) {
#pragma unroll
    for (int ct = 0; ct < 8; ct++) {
      int col = ct * 16 + l15;
      int lrow0 = w * 32 + rg * 16 + q4 * 4;
#pragma unroll
      for (int ri = 0; ri < 4; ri++) {
        int grow = rowbase + lrow0 + ri;
        float val = acc[rg][ct][ri];
        if (side == 0) {
          if (half == 0) pbf[grow * 128 + col] = f2bf(val + bp[col]);
          else           pAc[grow * 128 + col] = val + c1[col];
        } else {
          if (half == 0) vbf[grow * 128 + col] = f2bf(val + bv[col]);
          else {
            int btl = grow >> 5, m = grow & 31;
            int idx = btl * 4096 +
                      ((((m >> 4) * 4 + (col >> 5)) * 64) + ((m >> 3) & 1) * 32 + (col & 31)) * 8 +
                      (m & 7);
            vbsw[idx] = f2bf(val);   // 32x32x16 B-frag order, K index = m
          }
        }
      }
    }
  }
}

// ---------------------------------------------------------------------------
// k2: pair-interaction stage. grid=1024: bt = b>>2, n-slab = (b&3)*8.
// 4 waves, each wave 2 row-tiles (n, n+1) x 128 cols, 32x32x16 MFMA.
// z = x@W1c + y@W1d (x,y built from LDS p,v per fragment) + vB (indicator
// MFMA) + pAc (scalar add). h=silu(z) -> LDS transpose -> h_sw global in
// 16x16x32 A-frag order for k3.
// ---------------------------------------------------------------------------
__global__ __launch_bounds__(256, 2) void k2_pair(
    const unsigned short* __restrict__ pbf, const unsigned short* __restrict__ vbf,
    const float* __restrict__ pAc, const unsigned short* __restrict__ w1cd,
    const unsigned short* __restrict__ vbsw, unsigned short* __restrict__ hsw) {
  __shared__ __align__(16) unsigned short sVf[4096];        // v in 32x32x16 A-frag order
  __shared__ __align__(16) unsigned short sP[8 * 136];      // p rows (row-major, broadcast reads)
  __shared__ float sPA[8 * 128];
  __shared__ __align__(16) unsigned short sH[4][2][16 * 136];
  int bt = blockIdx.x >> 2, n0 = (blockIdx.x & 3) * 8;
  int tid = threadIdx.x;

  if (tid < 128) {  // stage p (8 rows)
    int row = tid >> 4, seg = tid & 15;
    *(uint4*)&sP[row * 136 + seg * 8] = *(const uint4*)(pbf + (bt * 32 + n0 + row) * 128 + seg * 8);
  }
#pragma unroll
  for (int g2 = 0; g2 < 2; g2++) {  // stage v in frag order: ((kt*2+hi)*32+m)*8+j, k=kt*16+hi*8+j
    int g = tid * 2 + g2;
    int m = g & 31, k0 = (g >> 5) * 8;
    *(uint4*)&sVf[g * 8] = *(const uint4*)(vbf + (bt * 32 + m) * 128 + k0);
  }
  {  // stage pAc (8 rows fp32)
    int row = tid >> 5, c4 = (tid & 31) * 4;
    *(float4*)&sPA[row * 128 + c4] = *(const float4*)(pAc + (bt * 32 + n0 + row) * 128 + c4);
  }
  __syncthreads();

  int lane = tid & 63, w = tid >> 6;
  int m31 = lane & 31, hi = lane >> 5, l15 = lane & 15, q4 = lane >> 4;
  int na = 2 * w, nb = 2 * w + 1;   // local n indices
  const unsigned short* vbswt = vbsw + bt * 4096;

  f32x16 acc0[4] = {};
  f32x16 acc1[4] = {};

#pragma unroll
  for (int kt = 0; kt < 8; kt++) {  // K=128 over x and y simultaneously
    short8 vf = *(const short8*)&sVf[((kt * 2 + hi) * 32 + m31) * 8];
    short8 p0 = *(const short8*)&sP[na * 136 + kt * 16 + hi * 8];
    short8 p1 = *(const short8*)&sP[nb * 136 + kt * 16 + hi * 8];
    short8 x0, y0, x1, y1;
#pragma unroll
    for (int j = 0; j < 8; j++) {
      float vv = bf2f((unsigned short)vf[j]);
      float a = bf2f((unsigned short)p0[j]);
      float c = bf2f((unsigned short)p1[j]);
      x0[j] = (short)f2bf(a * vv);
      y0[j] = (short)f2bf(fabsf(a - vv));
      x1[j] = (short)f2bf(c * vv);
      y1[j] = (short)f2bf(fabsf(c - vv));
    }
    const unsigned short* bxb = w1cd + (kt * 4) * 512;
    const unsigned short* byb = w1cd + ((kt + 8) * 4) * 512;
#pragma unroll
    for (int ct = 0; ct < 4; ct++) {
      short8 bx = *(const short8*)(bxb + ct * 512 + lane * 8);
      short8 by = *(const short8*)(byb + ct * 512 + lane * 8);
      acc0[ct] = __builtin_amdgcn_mfma_f32_32x32x16_bf16(x0, bx, acc0[ct], 0, 0, 0);
      acc1[ct] = __builtin_amdgcn_mfma_f32_32x32x16_bf16(x1, bx, acc1[ct], 0, 0, 0);
      acc0[ct] = __builtin_amdgcn_mfma_f32_32x32x16_bf16(y0, by, acc0[ct], 0, 0, 0);
      acc1[ct] = __builtin_amdgcn_mfma_f32_32x32x16_bf16(y1, by, acc1[ct], 0, 0, 0);
    }
  }

  // vB via indicator GEMM: A[r][k]=delta(r==k), B=vB (frag order), K=32
#pragma unroll
  for (int kt2 = 0; kt2 < 2; kt2++) {
    short8 indf;
#pragma unroll
    for (int j = 0; j < 8; j++)
      indf[j] = (short)(((kt2 * 16 + hi * 8 + j) == m31) ? 0x3F80 : 0);
#pragma unroll
    for (int ct = 0; ct < 4; ct++) {
      short8 bi = *(const short8*)(vbswt + (kt2 * 4 + ct) * 512 + lane * 8);
      acc0[ct] = __builtin_amdgcn_mfma_f32_32x32x16_bf16(indf, bi, acc0[ct], 0, 0, 0);
      acc1[ct] = __builtin_amdgcn_mfma_f32_32x32x16_bf16(indf, bi, acc1[ct], 0, 0, 0);
    }
  }

  // + pAc (constant per row-tile & col)
#pragma unroll
  for (int ct = 0; ct < 4; ct++) {
    float t0 = sPA[na * 128 + ct * 32 + m31];
    float t1 = sPA[nb * 128 + ct * 32 + m31];
#pragma unroll
    for (int i = 0; i < 16; i++) { acc0[ct][i] += t0; acc1[ct][i] += t1; }
  }

  // silu -> LDS transpose (16-row chunks) -> global h_sw in 16x16x32 A-frag order
  auto stage_store = [&](const f32x16* A, int nloc) {
#pragma unroll
    for (int ch = 0; ch < 2; ch++) {
      unsigned short* sHw = &sH[w][ch][0];
#pragma unroll
      for (int ct = 0; ct < 4; ct++) {
#pragma unroll
        for (int r8 = 0; r8 < 8; r8++) {
          int reg = ch * 8 + r8;
          float z = A[ct][reg];
          float hv = z / (1.f + __expf(-z));
          int row16 = (reg & 3) + 8 * ((reg >> 2) & 1) + 4 * hi;  // C-layout row within chunk
          sHw[row16 * 136 + ct * 32 + m31] = f2bf(hv);
        }
      }
      int rg = bt * 64 + nloc * 2 + ch;   // 16-row group index
#pragma unroll
      for (int kt2 = 0; kt2 < 4; kt2++) {
        uint4 fr = *(const uint4*)&sHw[l15 * 136 + kt2 * 32 + q4 * 8];
        *(uint4*)(hsw + ((rg * 4 + kt2) * 64 + lane) * 8) = fr;
      }
    }
  };
  stage_store(acc0, n0 + na);
  stage_store(acc1, n0 + nb);
}

// ---------------------------------------------------------------------------
// k3: out = h@W2 + b2. h read as pre-swizzled A-frags (coalesced). Memory-bound.
// grid=1024, block 256 (4 waves), wave = 4 row-groups of 16 x 128 cols.
// ---------------------------------------------------------------------------
__global__ __launch_bounds__(256, 2) void k3_out(
    const unsigned short* __restrict__ hsw, const unsigned short* __restrict__ w2sw,
    const float* __restrict__ b2, float* __restrict__ out) {
  __shared__ __align__(16) unsigned short sW2[16384];
  __shared__ float sB2[128];
  int tid = threadIdx.x;
#pragma unroll
  for (int i = 0; i < 8; i++) {
    int e = i * 256 + tid;
    *(uint4*)&sW2[e * 8] = *(const uint4*)(w2sw + e * 8);
  }
  if (tid < 128) sB2[tid] = b2[tid];
  __syncthreads();

  int lane = tid & 63, w = tid >> 6;
  int l15 = lane & 15, q4 = lane >> 4;
  int rg0 = blockIdx.x * 16 + w * 4;

  f32x4 acc[4][8] = {};
#pragma unroll
  for (int kt = 0; kt < 4; kt++) {
    short8 hf[4];
#pragma unroll
    for (int rgi = 0; rgi < 4; rgi++)
      hf[rgi] = *(const short8*)(hsw + (((rg0 + rgi) * 4 + kt) * 64 + lane) * 8);
#pragma unroll
    for (int ct = 0; ct < 8; ct++) {
      short8 bfr = *(const short8*)&sW2[((ct * 4 + kt) * 64 + lane) * 8];
#pragma unroll
      for (int rgi = 0; rgi < 4; rgi++)
        acc[rgi][ct] = __builtin_amdgcn_mfma_f32_16x16x32_bf16(hf[rgi], bfr, acc[rgi][ct], 0, 0, 0);
    }
  }
#pragma unroll
  for (int rgi = 0; rgi < 4; rgi++) {
    int growb = (rg0 + rgi) * 16 + q4 * 4;
#pragma unroll
    for (int ct = 0; ct < 8; ct++) {
      int col = ct * 16 + l15;
      float bias = sB2[col];
#pragma unroll
      for (int ri = 0; ri < 4; ri++)
        out[(growb + ri) * 128 + col] = acc[rgi][ct][ri] + bias;
    }
  }
}

// ---------------------------------------------------------------------------
extern "C" void kernel_launch(void* const* d_in, const int* in_sizes, int n_in,
                              void* d_out, int out_size, void* d_ws, size_t ws_size,
                              hipStream_t stream) {
  const float* price  = (const float*)d_in[0];
  const float* liquid = (const float*)d_in[1];
  const float* Wp     = (const float*)d_in[2];
  const float* bp     = (const float*)d_in[3];
  const float* Wv     = (const float*)d_in[4];
  const float* bv     = (const float*)d_in[5];
  const float* W1     = (const float*)d_in[6];
  const float* b1     = (const float*)d_in[7];
  const float* W2     = (const float*)d_in[8];
  const float* b2     = (const float*)d_in[9];

  char* ws = (char*)d_ws;
  unsigned short* w1cd = (unsigned short*)(ws + 0);         //  64 KB
  unsigned short* w2sw = (unsigned short*)(ws + 65536);     //  32 KB
  unsigned short* wpsw = (unsigned short*)(ws + 98304);     //  32 KB
  unsigned short* gpsw = (unsigned short*)(ws + 131072);    //  32 KB
  unsigned short* wvsw = (unsigned short*)(ws + 163840);    //  32 KB
  unsigned short* gvsw = (unsigned short*)(ws + 196608);    //  32 KB
  float*          c1   = (float*)(ws + 229376);             // 512 B
  unsigned short* pbf  = (unsigned short*)(ws + 262144);    //   2 MB
  unsigned short* vbf  = (unsigned short*)(ws + 2359296);   //   2 MB
  float*          pAc  = (float*)(ws + 4456448);            //   4 MB
  unsigned short* vbsw = (unsigned short*)(ws + 8650752);   //   2 MB
  unsigned short* hsw  = (unsigned short*)(ws + 10747904);  //  64 MB -> total ~74.3 MB

  hipLaunchKernelGGL(k0_prep, dim3(449), dim3(256), 0, stream,
                     Wp, bp, Wv, bv, W1, b1, W2, w1cd, w2sw, wpsw, gpsw, wvsw, gvsw, c1);
  hipLaunchKernelGGL(k1_proj, dim3(256), dim3(256), 0, stream,
                     price, liquid, bp, bv, c1, wpsw, gpsw, wvsw, gvsw, pbf, vbf, pAc, vbsw);
  hipLaunchKernelGGL(k2_pair, dim3(1024), dim3(256), 0, stream,
                     pbf, vbf, pAc, w1cd, vbsw, hsw);
  hipLaunchKernelGGL(k3_out, dim3(1024), dim3(256), 0, stream,
                     hsw, w2sw, b2, (float*)d_out);
}

// Round 2
// 242.814 us; speedup vs baseline: 1.0001x; 1.0001x over previous
//
#include <hip/hip_runtime.h>

// ---------------------------------------------------------------------------
// PairInteractionGrid: B=4,T=64,N=32,M=32,D=128
//   p = price@W_p + b_p ; v = liquid@W_v + b_v
//   z = p@W1a + v@W1b + (p*v)@W1c + |p-v|@W1d + b1   (W1 split in 4 K-blocks)
//   out = silu(z)@W2 + b2
// Decomposition: pA = price@(W_p@W1a)+c1 per n-row, vB = liquid@(W_v@W1b) per
// m-row -> only pair-dependent GEMMs ((p*v)@W1c, |p-v|@W1d, h@W2) run per
// pair. R2: k2+k3 fused — h never touches HBM (saves 128 MB round trip).
// ---------------------------------------------------------------------------

typedef short  short8  __attribute__((ext_vector_type(8)));
typedef float  f32x4   __attribute__((ext_vector_type(4)));
typedef float  f32x16  __attribute__((ext_vector_type(16)));

#define DEV static __device__ __forceinline__

DEV float bf2f(unsigned short h) {
  unsigned u = ((unsigned)h) << 16;
  float f;
  __builtin_memcpy(&f, &u, 4);
  return f;
}
DEV unsigned short f2bf(float f) {   // round-nearest-even
  unsigned u;
  __builtin_memcpy(&u, &f, 4);
  unsigned r = (u + 0x7FFFu + ((u >> 16) & 1u)) >> 16;
  return (unsigned short)r;
}

// ---------------------------------------------------------------------------
// k0: weight folding + fragment-order swizzles (tiny)
//  w1cd : [W1c;W1d] K=256 in 32x32x16 B-frag order: ((kt*4+ct)*64+lane)*8+j,
//         k=kt*16+(lane>>5)*8+j, c=ct*32+(lane&31). val=W1[256+k][c]
//  w2sw : W2 K=128 in 32x32x16 B-frag order (8 kt x 4 ct)
//  wpsw/gpsw/wvsw/gvsw : 16x16x32 B-frag order for k1
//  c1   : b_p@W1a + b_v@W1b + b1 (fp32)
// ---------------------------------------------------------------------------
__global__ void k0_prep(const float* __restrict__ Wp, const float* __restrict__ bp,
                        const float* __restrict__ Wv, const float* __restrict__ bv,
                        const float* __restrict__ W1, const float* __restrict__ b1,
                        const float* __restrict__ W2,
                        unsigned short* __restrict__ w1cd, unsigned short* __restrict__ w2sw,
                        unsigned short* __restrict__ wpsw, unsigned short* __restrict__ gpsw,
                        unsigned short* __restrict__ wvsw, unsigned short* __restrict__ gvsw,
                        float* __restrict__ c1) {
  int t = blockIdx.x * 256 + threadIdx.x;
  if (t < 32768) {                       // w1cd (32x32x16 B-frag, K=256)
    int j = t & 7, lane = (t >> 3) & 63, r2 = t >> 9;
    int ct = r2 & 3, kt = r2 >> 2;
    int k = kt * 16 + (lane >> 5) * 8 + j;
    int c = ct * 32 + (lane & 31);
    w1cd[t] = f2bf(W1[(256 + k) * 128 + c]);
  } else if (t < 114688) {
    int e = t - 32768;
    int sec = e >> 14;                   // 0:w2(32x32 frag) 1:wp 2:gp 3:wv 4:gv (16x16 frag)
    int f = e & 16383;
    int j = f & 7, lane = (f >> 3) & 63, r2 = f >> 9;
    if (sec == 0) {                      // 32x32x16 B-frag, K=128
      int ct = r2 & 3, kt = r2 >> 2;     // kt in [0,8)
      int k = kt * 16 + (lane >> 5) * 8 + j;
      int c = ct * 32 + (lane & 31);
      w2sw[f] = f2bf(W2[k * 128 + c]);
    } else {
      int kt = r2 & 3, ct = r2 >> 2;
      int k = kt * 32 + ((lane >> 4) & 3) * 8 + j;
      int n = ct * 16 + (lane & 15);
      if (sec == 1) {
        wpsw[f] = f2bf(Wp[k * 128 + n]);
      } else if (sec == 2) {
        float s = 0.f;
        for (int e2 = 0; e2 < 128; e2++) s += Wp[k * 128 + e2] * W1[e2 * 128 + n];
        gpsw[f] = f2bf(s);
      } else if (sec == 3) {
        wvsw[f] = f2bf(Wv[k * 128 + n]);
      } else {
        float s = 0.f;
        for (int e2 = 0; e2 < 128; e2++) s += Wv[k * 128 + e2] * W1[(128 + e2) * 128 + n];
        gvsw[f] = f2bf(s);
      }
    }
  } else if (t < 114816) {               // c1
    int c = t - 114688;
    float s = b1[c];
    for (int e2 = 0; e2 < 128; e2++)
      s += bp[e2] * W1[e2 * 128 + c] + bv[e2] * W1[(128 + e2) * 128 + c];
    c1[c] = s;
  }
}

// ---------------------------------------------------------------------------
// k1: projection GEMM. grid=256: b>>2 = 128-row chunk, b&3 = {side,half}
//  side0/half0: p_bf  = bf16(price@Wp + b_p)          [row][128]
//  side0/half1: pAc   = price@Gp + c1 (fp32)          [row][128]
//  side1/half0: v_bf  = bf16(liquid@Wv + b_v)         [row][128]
//  side1/half1: vbsw  = bf16(liquid@Gv) in 32x32x16 B-frag order per bt (K=32)
// ---------------------------------------------------------------------------
__global__ __launch_bounds__(256, 2) void k1_proj(
    const float* __restrict__ price, const float* __restrict__ liquid,
    const float* __restrict__ bp, const float* __restrict__ bv, const float* __restrict__ c1,
    const unsigned short* __restrict__ wpsw, const unsigned short* __restrict__ gpsw,
    const unsigned short* __restrict__ wvsw, const unsigned short* __restrict__ gvsw,
    unsigned short* __restrict__ pbf, unsigned short* __restrict__ vbf,
    float* __restrict__ pAc, unsigned short* __restrict__ vbsw) {
  __shared__ __align__(16) unsigned short sA[128 * 136];
  int b = blockIdx.x;
  int chunk = b >> 2, sel = b & 3;
  int side = sel >> 1, half = sel & 1;
  int rowbase = chunk * 128;
  const float* src = side ? liquid : price;
  const unsigned short* bsw = side ? (half ? gvsw : wvsw) : (half ? gpsw : wpsw);
  int tid = threadIdx.x;

#pragma unroll
  for (int i = 0; i < 16; i++) {
    int e4 = i * 256 + tid;
    int row = e4 >> 5, c4 = (e4 & 31) * 4;
    float4 f = *(const float4*)(src + (rowbase + row) * 128 + c4);
    unsigned u0 = (unsigned)f2bf(f.x) | ((unsigned)f2bf(f.y) << 16);
    unsigned u1 = (unsigned)f2bf(f.z) | ((unsigned)f2bf(f.w) << 16);
    uint2 pk; pk.x = u0; pk.y = u1;
    *(uint2*)&sA[row * 136 + c4] = pk;
  }
  __syncthreads();

  int lane = tid & 63, w = tid >> 6;
  int l15 = lane & 15, q4 = lane >> 4;
  f32x4 acc[2][8] = {};
#pragma unroll
  for (int kt = 0; kt < 4; kt++) {
    short8 a0 = *(const short8*)&sA[(w * 32 + l15) * 136 + kt * 32 + q4 * 8];
    short8 a1 = *(const short8*)&sA[(w * 32 + 16 + l15) * 136 + kt * 32 + q4 * 8];
#pragma unroll
    for (int ct = 0; ct < 8; ct++) {
      short8 bfr = *(const short8*)(bsw + ((ct * 4 + kt) * 64 + lane) * 8);
      acc[0][ct] = __builtin_amdgcn_mfma_f32_16x16x32_bf16(a0, bfr, acc[0][ct], 0, 0, 0);
      acc[1][ct] = __builtin_amdgcn_mfma_f32_16x16x32_bf16(a1, bfr, acc[1][ct], 0, 0, 0);
    }
  }

#pragma unroll
  for (int rg = 0; rg < 2; rg++) {
#pragma unroll
    for (int ct = 0; ct < 8; ct++) {
      int col = ct * 16 + l15;
      int lrow0 = w * 32 + rg * 16 + q4 * 4;
#pragma unroll
      for (int ri = 0; ri < 4; ri++) {
        int grow = rowbase + lrow0 + ri;
        float val = acc[rg][ct][ri];
        if (side == 0) {
          if (half == 0) pbf[grow * 128 + col] = f2bf(val + bp[col]);
          else           pAc[grow * 128 + col] = val + c1[col];
        } else {
          if (half == 0) vbf[grow * 128 + col] = f2bf(val + bv[col]);
          else {
            int btl = grow >> 5, m = grow & 31;
            int idx = btl * 4096 +
                      ((((m >> 4) * 4 + (col >> 5)) * 64) + ((m >> 3) & 1) * 32 + (col & 31)) * 8 +
                      (m & 7);
            vbsw[idx] = f2bf(val);   // 32x32x16 B-frag order, K index = m
          }
        }
      }
    }
  }
}

// ---------------------------------------------------------------------------
// k2_fused: pair stage + output GEMM. grid=1024: bt = b>>2, n-slab = (b&3)*8.
// 4 waves; wave w owns n rows {2w, 2w+1}. Per n: z = x@W1c + y@W1d + vB
// (indicator MFMA) + pAc; h = silu(z); transpose 32x128 h tile via private
// padded LDS into 32x32x16 A-frags; out = h@W2 + b2 written straight to HBM.
// Single __syncthreads; LDS 45 KB -> 2 blocks/CU.
// ---------------------------------------------------------------------------
__global__ __launch_bounds__(256, 2) void k2_fused(
    const unsigned short* __restrict__ pbf, const unsigned short* __restrict__ vbf,
    const float* __restrict__ pAc, const unsigned short* __restrict__ w1cd,
    const unsigned short* __restrict__ vbsw, const unsigned short* __restrict__ w2sw,
    const float* __restrict__ b2, float* __restrict__ out) {
  __shared__ __align__(16) unsigned short sVf[4096];        // v in 32x32x16 A-frag order
  __shared__ __align__(16) unsigned short sP[8 * 136];      // p rows (broadcast reads)
  __shared__ __align__(16) unsigned short sHt[4][32 * 136]; // per-wave transpose buffer
  int bt = blockIdx.x >> 2, n0 = (blockIdx.x & 3) * 8;
  int tid = threadIdx.x;

  if (tid < 128) {  // stage p (8 rows)
    int row = tid >> 4, seg = tid & 15;
    *(uint4*)&sP[row * 136 + seg * 8] = *(const uint4*)(pbf + (bt * 32 + n0 + row) * 128 + seg * 8);
  }
#pragma unroll
  for (int g2 = 0; g2 < 2; g2++) {  // stage v in A-frag order: ((kt*2+hi)*32+m)*8+j
    int g = tid * 2 + g2;
    int m = g & 31, k0 = (g >> 5) * 8;
    *(uint4*)&sVf[g * 8] = *(const uint4*)(vbf + (bt * 32 + m) * 128 + k0);
  }
  __syncthreads();

  int lane = tid & 63, w = tid >> 6;
  int m31 = lane & 31, hi = lane >> 5;
  int na = 2 * w, nb = 2 * w + 1;   // local n indices
  const unsigned short* vbswt = vbsw + bt * 4096;

  // per-lane constants: pAc rows, b2 bias
  float pa0[4], pa1[4], bia[4];
#pragma unroll
  for (int ct = 0; ct < 4; ct++) {
    pa0[ct] = pAc[(bt * 32 + n0 + na) * 128 + ct * 32 + m31];
    pa1[ct] = pAc[(bt * 32 + n0 + nb) * 128 + ct * 32 + m31];
    bia[ct] = b2[ct * 32 + m31];
  }

  f32x16 acc0[4] = {};
  f32x16 acc1[4] = {};

#pragma unroll
  for (int kt = 0; kt < 8; kt++) {  // K=128 over x=(p*v) and y=|p-v| together
    short8 vf = *(const short8*)&sVf[((kt * 2 + hi) * 32 + m31) * 8];
    short8 p0 = *(const short8*)&sP[na * 136 + kt * 16 + hi * 8];
    short8 p1 = *(const short8*)&sP[nb * 136 + kt * 16 + hi * 8];
    short8 x0, y0, x1, y1;
#pragma unroll
    for (int j = 0; j < 8; j++) {
      float vv = bf2f((unsigned short)vf[j]);
      float a = bf2f((unsigned short)p0[j]);
      float c = bf2f((unsigned short)p1[j]);
      x0[j] = (short)f2bf(a * vv);
      y0[j] = (short)f2bf(fabsf(a - vv));
      x1[j] = (short)f2bf(c * vv);
      y1[j] = (short)f2bf(fabsf(c - vv));
    }
    const unsigned short* bxb = w1cd + (kt * 4) * 512;
    const unsigned short* byb = w1cd + ((kt + 8) * 4) * 512;
#pragma unroll
    for (int ct = 0; ct < 4; ct++) {
      short8 bx = *(const short8*)(bxb + ct * 512 + lane * 8);
      short8 by = *(const short8*)(byb + ct * 512 + lane * 8);
      acc0[ct] = __builtin_amdgcn_mfma_f32_32x32x16_bf16(x0, bx, acc0[ct], 0, 0, 0);
      acc1[ct] = __builtin_amdgcn_mfma_f32_32x32x16_bf16(x1, bx, acc1[ct], 0, 0, 0);
      acc0[ct] = __builtin_amdgcn_mfma_f32_32x32x16_bf16(y0, by, acc0[ct], 0, 0, 0);
      acc1[ct] = __builtin_amdgcn_mfma_f32_32x32x16_bf16(y1, by, acc1[ct], 0, 0, 0);
    }
  }

  // vB via indicator GEMM: A[r][k]=delta(r==k), B=vB (frag order), K=32
#pragma unroll
  for (int kt2 = 0; kt2 < 2; kt2++) {
    short8 indf;
#pragma unroll
    for (int j = 0; j < 8; j++)
      indf[j] = (short)(((kt2 * 16 + hi * 8 + j) == m31) ? 0x3F80 : 0);
#pragma unroll
    for (int ct = 0; ct < 4; ct++) {
      short8 bi = *(const short8*)(vbswt + (kt2 * 4 + ct) * 512 + lane * 8);
      acc0[ct] = __builtin_amdgcn_mfma_f32_32x32x16_bf16(indf, bi, acc0[ct], 0, 0, 0);
      acc1[ct] = __builtin_amdgcn_mfma_f32_32x32x16_bf16(indf, bi, acc1[ct], 0, 0, 0);
    }
  }

  // + pAc (constant per row & col)
#pragma unroll
  for (int ct = 0; ct < 4; ct++) {
#pragma unroll
    for (int i = 0; i < 16; i++) { acc0[ct][i] += pa0[ct]; acc1[ct][i] += pa1[ct]; }
  }

  // per n: silu -> LDS transpose (32x136, conflict-free) -> h@W2+b2 -> out
  unsigned short* sh = &sHt[w][0];
  auto tail = [&](const f32x16* A, int n) {
#pragma unroll
    for (int ct = 0; ct < 4; ct++) {
#pragma unroll
      for (int reg = 0; reg < 16; reg++) {
        float z = A[ct][reg];
        float hv = z / (1.f + __expf(-z));
        int mr = (reg & 3) + 8 * (reg >> 2) + 4 * hi;   // C-layout row = pair m
        sh[mr * 136 + ct * 32 + m31] = f2bf(hv);
      }
    }
    short8 hf[8];
#pragma unroll
    for (int kt = 0; kt < 8; kt++)       // A-frag: row=lane&31, k=kt*16+hi*8..
      hf[kt] = *(const short8*)&sh[m31 * 136 + kt * 16 + hi * 8];
    f32x16 o[4] = {};
#pragma unroll
    for (int kt = 0; kt < 8; kt++) {
#pragma unroll
      for (int ct = 0; ct < 4; ct++) {
        short8 wf = *(const short8*)(w2sw + ((kt * 4 + ct) * 64 + lane) * 8);
        o[ct] = __builtin_amdgcn_mfma_f32_32x32x16_bf16(hf[kt], wf, o[ct], 0, 0, 0);
      }
    }
    int rowb = bt * 1024 + n * 32;
#pragma unroll
    for (int ct = 0; ct < 4; ct++) {
#pragma unroll
      for (int reg = 0; reg < 16; reg++) {
        int mr = (reg & 3) + 8 * (reg >> 2) + 4 * hi;
        out[(rowb + mr) * 128 + ct * 32 + m31] = o[ct][reg] + bia[ct];
      }
    }
  };
  tail(acc0, n0 + na);
  tail(acc1, n0 + nb);
}

// ---------------------------------------------------------------------------
extern "C" void kernel_launch(void* const* d_in, const int* in_sizes, int n_in,
                              void* d_out, int out_size, void* d_ws, size_t ws_size,
                              hipStream_t stream) {
  const float* price  = (const float*)d_in[0];
  const float* liquid = (const float*)d_in[1];
  const float* Wp     = (const float*)d_in[2];
  const float* bp     = (const float*)d_in[3];
  const float* Wv     = (const float*)d_in[4];
  const float* bv     = (const float*)d_in[5];
  const float* W1     = (const float*)d_in[6];
  const float* b1     = (const float*)d_in[7];
  const float* W2     = (const float*)d_in[8];
  const float* b2     = (const float*)d_in[9];

  char* ws = (char*)d_ws;
  unsigned short* w1cd = (unsigned short*)(ws + 0);         //  64 KB
  unsigned short* w2sw = (unsigned short*)(ws + 65536);     //  32 KB
  unsigned short* wpsw = (unsigned short*)(ws + 98304);     //  32 KB
  unsigned short* gpsw = (unsigned short*)(ws + 131072);    //  32 KB
  unsigned short* wvsw = (unsigned short*)(ws + 163840);    //  32 KB
  unsigned short* gvsw = (unsigned short*)(ws + 196608);    //  32 KB
  float*          c1   = (float*)(ws + 229376);             // 512 B
  unsigned short* pbf  = (unsigned short*)(ws + 262144);    //   2 MB
  unsigned short* vbf  = (unsigned short*)(ws + 2359296);   //   2 MB
  float*          pAc  = (float*)(ws + 4456448);            //   4 MB
  unsigned short* vbsw = (unsigned short*)(ws + 8650752);   //   2 MB -> total ~10.3 MB

  hipLaunchKernelGGL(k0_prep, dim3(449), dim3(256), 0, stream,
                     Wp, bp, Wv, bv, W1, b1, W2, w1cd, w2sw, wpsw, gpsw, wvsw, gvsw, c1);
  hipLaunchKernelGGL(k1_proj, dim3(256), dim3(256), 0, stream,
                     price, liquid, bp, bv, c1, wpsw, gpsw, wvsw, gvsw, pbf, vbf, pAc, vbsw);
  hipLaunchKernelGGL(k2_fused, dim3(1024), dim3(256), 0, stream,
                     pbf, vbf, pAc, w1cd, vbsw, w2sw, b2, (float*)d_out);
}

// Round 3
// 242.723 us; speedup vs baseline: 1.0004x; 1.0004x over previous
//
#include <hip/hip_runtime.h>

// ---------------------------------------------------------------------------
// PairInteractionGrid: B=4,T=64,N=32,M=32,D=128
//   p = price@W_p + b_p ; v = liquid@W_v + b_v
//   z = p@W1a + v@W1b + (p*v)@W1c + |p-v|@W1d + b1
//   out = silu(z)@W2 + b2
// R3: k2 fragment construction via v_perm pairwise bf16 truncation (was
// scalar RNE f2bf — 4x VALU cut), rcp-based silu, 2-pass 32x72 LDS transpose
// (LDS 45.5 -> 28.8 KB).
// ---------------------------------------------------------------------------

typedef short  short8  __attribute__((ext_vector_type(8)));
typedef float  f32x4   __attribute__((ext_vector_type(4)));
typedef float  f32x16  __attribute__((ext_vector_type(16)));

#define DEV static __device__ __forceinline__

DEV float bf2f(unsigned short h) {
  unsigned u = ((unsigned)h) << 16;
  float f;
  __builtin_memcpy(&f, &u, 4);
  return f;
}
DEV unsigned short f2bf(float f) {   // round-nearest-even (k0/k1 only)
  unsigned u;
  __builtin_memcpy(&u, &f, 4);
  unsigned r = (u + 0x7FFFu + ((u >> 16) & 1u)) >> 16;
  return (unsigned short)r;
}
// pack two fp32 -> [bf16(fh) | bf16(fl)] by truncation: one v_perm_b32
DEV unsigned pk2(float fh, float fl) {
  return __builtin_amdgcn_perm(__float_as_uint(fh), __float_as_uint(fl), 0x07060302u);
}
DEV float lo16(unsigned u) { return __uint_as_float(u << 16); }
DEV float hi16(unsigned u) { return __uint_as_float(u & 0xFFFF0000u); }

union V8 { uint4 u; unsigned a[4]; short8 s; };

// ---------------------------------------------------------------------------
// k0: weight folding + fragment-order swizzles (tiny)
// ---------------------------------------------------------------------------
__global__ void k0_prep(const float* __restrict__ Wp, const float* __restrict__ bp,
                        const float* __restrict__ Wv, const float* __restrict__ bv,
                        const float* __restrict__ W1, const float* __restrict__ b1,
                        const float* __restrict__ W2,
                        unsigned short* __restrict__ w1cd, unsigned short* __restrict__ w2sw,
                        unsigned short* __restrict__ wpsw, unsigned short* __restrict__ gpsw,
                        unsigned short* __restrict__ wvsw, unsigned short* __restrict__ gvsw,
                        float* __restrict__ c1) {
  int t = blockIdx.x * 256 + threadIdx.x;
  if (t < 32768) {                       // w1cd (32x32x16 B-frag, K=256)
    int j = t & 7, lane = (t >> 3) & 63, r2 = t >> 9;
    int ct = r2 & 3, kt = r2 >> 2;
    int k = kt * 16 + (lane >> 5) * 8 + j;
    int c = ct * 32 + (lane & 31);
    w1cd[t] = f2bf(W1[(256 + k) * 128 + c]);
  } else if (t < 114688) {
    int e = t - 32768;
    int sec = e >> 14;                   // 0:w2(32x32 frag) 1:wp 2:gp 3:wv 4:gv (16x16 frag)
    int f = e & 16383;
    int j = f & 7, lane = (f >> 3) & 63, r2 = f >> 9;
    if (sec == 0) {                      // 32x32x16 B-frag, K=128
      int ct = r2 & 3, kt = r2 >> 2;     // kt in [0,8)
      int k = kt * 16 + (lane >> 5) * 8 + j;
      int c = ct * 32 + (lane & 31);
      w2sw[f] = f2bf(W2[k * 128 + c]);
    } else {
      int kt = r2 & 3, ct = r2 >> 2;
      int k = kt * 32 + ((lane >> 4) & 3) * 8 + j;
      int n = ct * 16 + (lane & 15);
      if (sec == 1) {
        wpsw[f] = f2bf(Wp[k * 128 + n]);
      } else if (sec == 2) {
        float s = 0.f;
        for (int e2 = 0; e2 < 128; e2++) s += Wp[k * 128 + e2] * W1[e2 * 128 + n];
        gpsw[f] = f2bf(s);
      } else if (sec == 3) {
        wvsw[f] = f2bf(Wv[k * 128 + n]);
      } else {
        float s = 0.f;
        for (int e2 = 0; e2 < 128; e2++) s += Wv[k * 128 + e2] * W1[(128 + e2) * 128 + n];
        gvsw[f] = f2bf(s);
      }
    }
  } else if (t < 114816) {               // c1
    int c = t - 114688;
    float s = b1[c];
    for (int e2 = 0; e2 < 128; e2++)
      s += bp[e2] * W1[e2 * 128 + c] + bv[e2] * W1[(128 + e2) * 128 + c];
    c1[c] = s;
  }
}

// ---------------------------------------------------------------------------
// k1: projection GEMM. grid=256: b>>2 = 128-row chunk, b&3 = {side,half}
// ---------------------------------------------------------------------------
__global__ __launch_bounds__(256, 2) void k1_proj(
    const float* __restrict__ price, const float* __restrict__ liquid,
    const float* __restrict__ bp, const float* __restrict__ bv, const float* __restrict__ c1,
    const unsigned short* __restrict__ wpsw, const unsigned short* __restrict__ gpsw,
    const unsigned short* __restrict__ wvsw, const unsigned short* __restrict__ gvsw,
    unsigned short* __restrict__ pbf, unsigned short* __restrict__ vbf,
    float* __restrict__ pAc, unsigned short* __restrict__ vbsw) {
  __shared__ __align__(16) unsigned short sA[128 * 136];
  int b = blockIdx.x;
  int chunk = b >> 2, sel = b & 3;
  int side = sel >> 1, half = sel & 1;
  int rowbase = chunk * 128;
  const float* src = side ? liquid : price;
  const unsigned short* bsw = side ? (half ? gvsw : wvsw) : (half ? gpsw : wpsw);
  int tid = threadIdx.x;

#pragma unroll
  for (int i = 0; i < 16; i++) {
    int e4 = i * 256 + tid;
    int row = e4 >> 5, c4 = (e4 & 31) * 4;
    float4 f = *(const float4*)(src + (rowbase + row) * 128 + c4);
    uint2 pk;
    pk.x = pk2(f.y, f.x);   // truncation is fine for GEMM inputs
    pk.y = pk2(f.w, f.z);
    *(uint2*)&sA[row * 136 + c4] = pk;
  }
  __syncthreads();

  int lane = tid & 63, w = tid >> 6;
  int l15 = lane & 15, q4 = lane >> 4;
  f32x4 acc[2][8] = {};
#pragma unroll
  for (int kt = 0; kt < 4; kt++) {
    short8 a0 = *(const short8*)&sA[(w * 32 + l15) * 136 + kt * 32 + q4 * 8];
    short8 a1 = *(const short8*)&sA[(w * 32 + 16 + l15) * 136 + kt * 32 + q4 * 8];
#pragma unroll
    for (int ct = 0; ct < 8; ct++) {
      short8 bfr = *(const short8*)(bsw + ((ct * 4 + kt) * 64 + lane) * 8);
      acc[0][ct] = __builtin_amdgcn_mfma_f32_16x16x32_bf16(a0, bfr, acc[0][ct], 0, 0, 0);
      acc[1][ct] = __builtin_amdgcn_mfma_f32_16x16x32_bf16(a1, bfr, acc[1][ct], 0, 0, 0);
    }
  }

#pragma unroll
  for (int rg = 0; rg < 2; rg++) {
#pragma unroll
    for (int ct = 0; ct < 8; ct++) {
      int col = ct * 16 + l15;
      int lrow0 = w * 32 + rg * 16 + q4 * 4;
#pragma unroll
      for (int ri = 0; ri < 4; ri++) {
        int grow = rowbase + lrow0 + ri;
        float val = acc[rg][ct][ri];
        if (side == 0) {
          if (half == 0) pbf[grow * 128 + col] = f2bf(val + bp[col]);
          else           pAc[grow * 128 + col] = val + c1[col];
        } else {
          if (half == 0) vbf[grow * 128 + col] = f2bf(val + bv[col]);
          else {
            int btl = grow >> 5, m = grow & 31;
            int idx = btl * 4096 +
                      ((((m >> 4) * 4 + (col >> 5)) * 64) + ((m >> 3) & 1) * 32 + (col & 31)) * 8 +
                      (m & 7);
            vbsw[idx] = f2bf(val);   // 32x32x16 B-frag order, K index = m
          }
        }
      }
    }
  }
}

// ---------------------------------------------------------------------------
// k2_fused: pair stage + output GEMM. grid=1024: bt = b>>2, n-slab = (b&3)*8.
// 4 waves; wave w owns n rows {2w, 2w+1}. Fragment construction via v_perm
// pairwise truncation; tail: silu (rcp), 2-pass 32x72 per-wave LDS transpose,
// out = h@W2 + b2 straight to HBM.
// ---------------------------------------------------------------------------
__global__ __launch_bounds__(256, 2) void k2_fused(
    const unsigned short* __restrict__ pbf, const unsigned short* __restrict__ vbf,
    const float* __restrict__ pAc, const unsigned short* __restrict__ w1cd,
    const unsigned short* __restrict__ vbsw, const unsigned short* __restrict__ w2sw,
    const float* __restrict__ b2, float* __restrict__ out) {
  __shared__ __align__(16) unsigned short sVf[4096];        // v in 32x32x16 A-frag order (8 KB)
  __shared__ __align__(16) unsigned short sP[8 * 136];      // p rows (2.2 KB)
  __shared__ __align__(16) unsigned short sHt[4][32 * 72];  // per-wave transpose buf (18.4 KB)
  int bt = blockIdx.x >> 2, n0 = (blockIdx.x & 3) * 8;
  int tid = threadIdx.x;

  if (tid < 128) {  // stage p (8 rows)
    int row = tid >> 4, seg = tid & 15;
    *(uint4*)&sP[row * 136 + seg * 8] = *(const uint4*)(pbf + (bt * 32 + n0 + row) * 128 + seg * 8);
  }
#pragma unroll
  for (int g2 = 0; g2 < 2; g2++) {  // stage v in A-frag order: ((kt*2+hi)*32+m)*8+j
    int g = tid * 2 + g2;
    int m = g & 31, k0 = (g >> 5) * 8;
    *(uint4*)&sVf[g * 8] = *(const uint4*)(vbf + (bt * 32 + m) * 128 + k0);
  }
  __syncthreads();

  int lane = tid & 63, w = tid >> 6;
  int m31 = lane & 31, hi = lane >> 5;
  int na = 2 * w, nb = 2 * w + 1;   // local n indices
  const unsigned short* vbswt = vbsw + bt * 4096;

  // per-lane constants: pAc rows, b2 bias
  float pa0[4], pa1[4], bia[4];
#pragma unroll
  for (int ct = 0; ct < 4; ct++) {
    pa0[ct] = pAc[(bt * 32 + n0 + na) * 128 + ct * 32 + m31];
    pa1[ct] = pAc[(bt * 32 + n0 + nb) * 128 + ct * 32 + m31];
    bia[ct] = b2[ct * 32 + m31];
  }

  f32x16 acc0[4] = {};
  f32x16 acc1[4] = {};

#pragma unroll
  for (int kt = 0; kt < 8; kt++) {  // K=128 over x=(p*v) and y=|p-v| together
    V8 vf, p0, p1, x0, y0, x1, y1;
    vf.u = *(const uint4*)&sVf[((kt * 2 + hi) * 32 + m31) * 8];
    p0.u = *(const uint4*)&sP[na * 136 + kt * 16 + hi * 8];
    p1.u = *(const uint4*)&sP[nb * 136 + kt * 16 + hi * 8];
#pragma unroll
    for (int i = 0; i < 4; i++) {
      float vl = lo16(vf.a[i]), vh = hi16(vf.a[i]);
      float al = lo16(p0.a[i]), ah = hi16(p0.a[i]);
      float cl = lo16(p1.a[i]), ch = hi16(p1.a[i]);
      x0.a[i] = pk2(ah * vh, al * vl);
      y0.a[i] = pk2(fabsf(ah - vh), fabsf(al - vl));
      x1.a[i] = pk2(ch * vh, cl * vl);
      y1.a[i] = pk2(fabsf(ch - vh), fabsf(cl - vl));
    }
    const unsigned short* bxb = w1cd + (kt * 4) * 512;
    const unsigned short* byb = w1cd + ((kt + 8) * 4) * 512;
#pragma unroll
    for (int ct = 0; ct < 4; ct++) {
      short8 bx = *(const short8*)(bxb + ct * 512 + lane * 8);
      short8 by = *(const short8*)(byb + ct * 512 + lane * 8);
      acc0[ct] = __builtin_amdgcn_mfma_f32_32x32x16_bf16(x0.s, bx, acc0[ct], 0, 0, 0);
      acc1[ct] = __builtin_amdgcn_mfma_f32_32x32x16_bf16(x1.s, bx, acc1[ct], 0, 0, 0);
      acc0[ct] = __builtin_amdgcn_mfma_f32_32x32x16_bf16(y0.s, by, acc0[ct], 0, 0, 0);
      acc1[ct] = __builtin_amdgcn_mfma_f32_32x32x16_bf16(y1.s, by, acc1[ct], 0, 0, 0);
    }
  }

  // vB via indicator GEMM: A[r][k]=delta(r==k), B=vB (frag order), K=32
#pragma unroll
  for (int kt2 = 0; kt2 < 2; kt2++) {
    short8 indf;
#pragma unroll
    for (int j = 0; j < 8; j++)
      indf[j] = (short)(((kt2 * 16 + hi * 8 + j) == m31) ? 0x3F80 : 0);
#pragma unroll
    for (int ct = 0; ct < 4; ct++) {
      short8 bi = *(const short8*)(vbswt + (kt2 * 4 + ct) * 512 + lane * 8);
      acc0[ct] = __builtin_amdgcn_mfma_f32_32x32x16_bf16(indf, bi, acc0[ct], 0, 0, 0);
      acc1[ct] = __builtin_amdgcn_mfma_f32_32x32x16_bf16(indf, bi, acc1[ct], 0, 0, 0);
    }
  }

  // + pAc (constant per row & col)
#pragma unroll
  for (int ct = 0; ct < 4; ct++) {
#pragma unroll
    for (int i = 0; i < 16; i++) { acc0[ct][i] += pa0[ct]; acc1[ct][i] += pa1[ct]; }
  }

  // per n: silu -> 2-pass LDS transpose (32x72, per-wave) -> h@W2+b2 -> out
  unsigned short* sh = &sHt[w][0];
  auto tail = [&](const f32x16* A, int n) {
    f32x16 o[4] = {};
#pragma unroll
    for (int p = 0; p < 2; p++) {
#pragma unroll
      for (int c2 = 0; c2 < 2; c2++) {
        int ct = p * 2 + c2;
#pragma unroll
        for (int reg = 0; reg < 16; reg++) {
          float z = A[ct][reg];
          float hv = z * __builtin_amdgcn_rcpf(1.f + __expf(-z));
          int mr = (reg & 3) + 8 * (reg >> 2) + 4 * hi;   // C-layout row = pair m
          sh[mr * 72 + c2 * 32 + m31] = (unsigned short)(__float_as_uint(hv) >> 16);
        }
      }
#pragma unroll
      for (int kt = 0; kt < 4; kt++) {
        int ktg = p * 4 + kt;
        short8 hf = *(const short8*)&sh[m31 * 72 + kt * 16 + hi * 8];
#pragma unroll
        for (int ct = 0; ct < 4; ct++) {
          short8 wf = *(const short8*)(w2sw + ((ktg * 4 + ct) * 64 + lane) * 8);
          o[ct] = __builtin_amdgcn_mfma_f32_32x32x16_bf16(hf, wf, o[ct], 0, 0, 0);
        }
      }
    }
    int rowb = bt * 1024 + n * 32;
#pragma unroll
    for (int ct = 0; ct < 4; ct++) {
#pragma unroll
      for (int reg = 0; reg < 16; reg++) {
        int mr = (reg & 3) + 8 * (reg >> 2) + 4 * hi;
        out[(rowb + mr) * 128 + ct * 32 + m31] = o[ct][reg] + bia[ct];
      }
    }
  };
  tail(acc0, n0 + na);
  tail(acc1, n0 + nb);
}

// ---------------------------------------------------------------------------
extern "C" void kernel_launch(void* const* d_in, const int* in_sizes, int n_in,
                              void* d_out, int out_size, void* d_ws, size_t ws_size,
                              hipStream_t stream) {
  const float* price  = (const float*)d_in[0];
  const float* liquid = (const float*)d_in[1];
  const float* Wp     = (const float*)d_in[2];
  const float* bp     = (const float*)d_in[3];
  const float* Wv     = (const float*)d_in[4];
  const float* bv     = (const float*)d_in[5];
  const float* W1     = (const float*)d_in[6];
  const float* b1     = (const float*)d_in[7];
  const float* W2     = (const float*)d_in[8];
  const float* b2     = (const float*)d_in[9];

  char* ws = (char*)d_ws;
  unsigned short* w1cd = (unsigned short*)(ws + 0);         //  64 KB
  unsigned short* w2sw = (unsigned short*)(ws + 65536);     //  32 KB
  unsigned short* wpsw = (unsigned short*)(ws + 98304);     //  32 KB
  unsigned short* gpsw = (unsigned short*)(ws + 131072);    //  32 KB
  unsigned short* wvsw = (unsigned short*)(ws + 163840);    //  32 KB
  unsigned short* gvsw = (unsigned short*)(ws + 196608);    //  32 KB
  float*          c1   = (float*)(ws + 229376);             // 512 B
  unsigned short* pbf  = (unsigned short*)(ws + 262144);    //   2 MB
  unsigned short* vbf  = (unsigned short*)(ws + 2359296);   //   2 MB
  float*          pAc  = (float*)(ws + 4456448);            //   4 MB
  unsigned short* vbsw = (unsigned short*)(ws + 8650752);   //   2 MB -> total ~10.3 MB

  hipLaunchKernelGGL(k0_prep, dim3(449), dim3(256), 0, stream,
                     Wp, bp, Wv, bv, W1, b1, W2, w1cd, w2sw, wpsw, gpsw, wvsw, gvsw, c1);
  hipLaunchKernelGGL(k1_proj, dim3(256), dim3(256), 0, stream,
                     price, liquid, bp, bv, c1, wpsw, gpsw, wvsw, gvsw, pbf, vbf, pAc, vbsw);
  hipLaunchKernelGGL(k2_fused, dim3(1024), dim3(256), 0, stream,
                     pbf, vbf, pAc, w1cd, vbsw, w2sw, b2, (float*)d_out);
}

// Round 4
// 212.997 us; speedup vs baseline: 1.1401x; 1.1396x over previous
//
#include <hip/hip_runtime.h>

// ---------------------------------------------------------------------------
// PairInteractionGrid: B=4,T=64,N=32,M=32,D=128
//   p = price@W_p + b_p ; v = liquid@W_v + b_v
//   z = p@W1a + v@W1b + (p*v)@W1c + |p-v|@W1d + b1
//   out = silu(z)@W2 + b2
// R4: k2 restructured to 1 n-row per wave (grid 2048). Halves accumulator
// footprint (z=64 regs, was 128) -> 3 waves/SIMD (launch_bounds(256,3)),
// 2x wave count for latency hiding. pAc folded into silu.
// ---------------------------------------------------------------------------

typedef short  short8  __attribute__((ext_vector_type(8)));
typedef float  f32x4   __attribute__((ext_vector_type(4)));
typedef float  f32x16  __attribute__((ext_vector_type(16)));

#define DEV static __device__ __forceinline__

DEV float bf2f(unsigned short h) {
  unsigned u = ((unsigned)h) << 16;
  float f;
  __builtin_memcpy(&f, &u, 4);
  return f;
}
DEV unsigned short f2bf(float f) {   // round-nearest-even (k0/k1 only)
  unsigned u;
  __builtin_memcpy(&u, &f, 4);
  unsigned r = (u + 0x7FFFu + ((u >> 16) & 1u)) >> 16;
  return (unsigned short)r;
}
// pack two fp32 -> [bf16(fh) | bf16(fl)] by truncation: one v_perm_b32
DEV unsigned pk2(float fh, float fl) {
  return __builtin_amdgcn_perm(__float_as_uint(fh), __float_as_uint(fl), 0x07060302u);
}
DEV float lo16(unsigned u) { return __uint_as_float(u << 16); }
DEV float hi16(unsigned u) { return __uint_as_float(u & 0xFFFF0000u); }

union V8 { uint4 u; unsigned a[4]; short8 s; };

// ---------------------------------------------------------------------------
// k0: weight folding + fragment-order swizzles (tiny)
// ---------------------------------------------------------------------------
__global__ void k0_prep(const float* __restrict__ Wp, const float* __restrict__ bp,
                        const float* __restrict__ Wv, const float* __restrict__ bv,
                        const float* __restrict__ W1, const float* __restrict__ b1,
                        const float* __restrict__ W2,
                        unsigned short* __restrict__ w1cd, unsigned short* __restrict__ w2sw,
                        unsigned short* __restrict__ wpsw, unsigned short* __restrict__ gpsw,
                        unsigned short* __restrict__ wvsw, unsigned short* __restrict__ gvsw,
                        float* __restrict__ c1) {
  int t = blockIdx.x * 256 + threadIdx.x;
  if (t < 32768) {                       // w1cd (32x32x16 B-frag, K=256)
    int j = t & 7, lane = (t >> 3) & 63, r2 = t >> 9;
    int ct = r2 & 3, kt = r2 >> 2;
    int k = kt * 16 + (lane >> 5) * 8 + j;
    int c = ct * 32 + (lane & 31);
    w1cd[t] = f2bf(W1[(256 + k) * 128 + c]);
  } else if (t < 114688) {
    int e = t - 32768;
    int sec = e >> 14;                   // 0:w2(32x32 frag) 1:wp 2:gp 3:wv 4:gv (16x16 frag)
    int f = e & 16383;
    int j = f & 7, lane = (f >> 3) & 63, r2 = f >> 9;
    if (sec == 0) {                      // 32x32x16 B-frag, K=128
      int ct = r2 & 3, kt = r2 >> 2;     // kt in [0,8)
      int k = kt * 16 + (lane >> 5) * 8 + j;
      int c = ct * 32 + (lane & 31);
      w2sw[f] = f2bf(W2[k * 128 + c]);
    } else {
      int kt = r2 & 3, ct = r2 >> 2;
      int k = kt * 32 + ((lane >> 4) & 3) * 8 + j;
      int n = ct * 16 + (lane & 15);
      if (sec == 1) {
        wpsw[f] = f2bf(Wp[k * 128 + n]);
      } else if (sec == 2) {
        float s = 0.f;
        for (int e2 = 0; e2 < 128; e2++) s += Wp[k * 128 + e2] * W1[e2 * 128 + n];
        gpsw[f] = f2bf(s);
      } else if (sec == 3) {
        wvsw[f] = f2bf(Wv[k * 128 + n]);
      } else {
        float s = 0.f;
        for (int e2 = 0; e2 < 128; e2++) s += Wv[k * 128 + e2] * W1[(128 + e2) * 128 + n];
        gvsw[f] = f2bf(s);
      }
    }
  } else if (t < 114816) {               // c1
    int c = t - 114688;
    float s = b1[c];
    for (int e2 = 0; e2 < 128; e2++)
      s += bp[e2] * W1[e2 * 128 + c] + bv[e2] * W1[(128 + e2) * 128 + c];
    c1[c] = s;
  }
}

// ---------------------------------------------------------------------------
// k1: projection GEMM. grid=256: b>>2 = 128-row chunk, b&3 = {side,half}
// ---------------------------------------------------------------------------
__global__ __launch_bounds__(256, 2) void k1_proj(
    const float* __restrict__ price, const float* __restrict__ liquid,
    const float* __restrict__ bp, const float* __restrict__ bv, const float* __restrict__ c1,
    const unsigned short* __restrict__ wpsw, const unsigned short* __restrict__ gpsw,
    const unsigned short* __restrict__ wvsw, const unsigned short* __restrict__ gvsw,
    unsigned short* __restrict__ pbf, unsigned short* __restrict__ vbf,
    float* __restrict__ pAc, unsigned short* __restrict__ vbsw) {
  __shared__ __align__(16) unsigned short sA[128 * 136];
  int b = blockIdx.x;
  int chunk = b >> 2, sel = b & 3;
  int side = sel >> 1, half = sel & 1;
  int rowbase = chunk * 128;
  const float* src = side ? liquid : price;
  const unsigned short* bsw = side ? (half ? gvsw : wvsw) : (half ? gpsw : wpsw);
  int tid = threadIdx.x;

#pragma unroll
  for (int i = 0; i < 16; i++) {
    int e4 = i * 256 + tid;
    int row = e4 >> 5, c4 = (e4 & 31) * 4;
    float4 f = *(const float4*)(src + (rowbase + row) * 128 + c4);
    uint2 pk;
    pk.x = pk2(f.y, f.x);   // truncation is fine for GEMM inputs
    pk.y = pk2(f.w, f.z);
    *(uint2*)&sA[row * 136 + c4] = pk;
  }
  __syncthreads();

  int lane = tid & 63, w = tid >> 6;
  int l15 = lane & 15, q4 = lane >> 4;
  f32x4 acc[2][8] = {};
#pragma unroll
  for (int kt = 0; kt < 4; kt++) {
    short8 a0 = *(const short8*)&sA[(w * 32 + l15) * 136 + kt * 32 + q4 * 8];
    short8 a1 = *(const short8*)&sA[(w * 32 + 16 + l15) * 136 + kt * 32 + q4 * 8];
#pragma unroll
    for (int ct = 0; ct < 8; ct++) {
      short8 bfr = *(const short8*)(bsw + ((ct * 4 + kt) * 64 + lane) * 8);
      acc[0][ct] = __builtin_amdgcn_mfma_f32_16x16x32_bf16(a0, bfr, acc[0][ct], 0, 0, 0);
      acc[1][ct] = __builtin_amdgcn_mfma_f32_16x16x32_bf16(a1, bfr, acc[1][ct], 0, 0, 0);
    }
  }

#pragma unroll
  for (int rg = 0; rg < 2; rg++) {
#pragma unroll
    for (int ct = 0; ct < 8; ct++) {
      int col = ct * 16 + l15;
      int lrow0 = w * 32 + rg * 16 + q4 * 4;
#pragma unroll
      for (int ri = 0; ri < 4; ri++) {
        int grow = rowbase + lrow0 + ri;
        float val = acc[rg][ct][ri];
        if (side == 0) {
          if (half == 0) pbf[grow * 128 + col] = f2bf(val + bp[col]);
          else           pAc[grow * 128 + col] = val + c1[col];
        } else {
          if (half == 0) vbf[grow * 128 + col] = f2bf(val + bv[col]);
          else {
            int btl = grow >> 5, m = grow & 31;
            int idx = btl * 4096 +
                      ((((m >> 4) * 4 + (col >> 5)) * 64) + ((m >> 3) & 1) * 32 + (col & 31)) * 8 +
                      (m & 7);
            vbsw[idx] = f2bf(val);   // 32x32x16 B-frag order, K index = m
          }
        }
      }
    }
  }
}

// ---------------------------------------------------------------------------
// k2_fused: pair stage + output GEMM. grid=2048: bt = b>>3, slab = (b&7)*4.
// 4 waves; wave w owns n = slab+w (ONE n-row slice of 32 m x 128 c).
// z accs = 64 regs -> 3 waves/SIMD. Fragment construction via v_perm
// truncation; tail: silu (pAc folded), 2-pass 32x72 per-wave LDS transpose,
// out = h@W2 + b2 straight to HBM.
// ---------------------------------------------------------------------------
__global__ __launch_bounds__(256, 3) void k2_fused(
    const unsigned short* __restrict__ pbf, const unsigned short* __restrict__ vbf,
    const float* __restrict__ pAc, const unsigned short* __restrict__ w1cd,
    const unsigned short* __restrict__ vbsw, const unsigned short* __restrict__ w2sw,
    const float* __restrict__ b2, float* __restrict__ out) {
  __shared__ __align__(16) unsigned short sVf[4096];        // v in 32x32x16 A-frag order (8 KB)
  __shared__ __align__(16) unsigned short sP[4 * 136];      // p rows for this slab (1.1 KB)
  __shared__ __align__(16) unsigned short sHt[4][32 * 72];  // per-wave transpose buf (18.4 KB)
  int bt = blockIdx.x >> 3, slab = (blockIdx.x & 7) * 4;
  int tid = threadIdx.x;

  if (tid < 64) {  // stage p (4 rows)
    int row = tid >> 4, seg = tid & 15;
    *(uint4*)&sP[row * 136 + seg * 8] = *(const uint4*)(pbf + (bt * 32 + slab + row) * 128 + seg * 8);
  }
#pragma unroll
  for (int g2 = 0; g2 < 2; g2++) {  // stage v in A-frag order: ((kt*2+hi)*32+m)*8+j
    int g = tid * 2 + g2;
    int m = g & 31, k0 = (g >> 5) * 8;
    *(uint4*)&sVf[g * 8] = *(const uint4*)(vbf + (bt * 32 + m) * 128 + k0);
  }
  __syncthreads();

  int lane = tid & 63, w = tid >> 6;
  int m31 = lane & 31, hi = lane >> 5;
  int n = slab + w;                 // this wave's n row
  const unsigned short* vbswt = vbsw + bt * 4096;

  // per-lane constants: pAc row (per ct col-block), b2 bias
  float pa[4], bia[4];
#pragma unroll
  for (int ct = 0; ct < 4; ct++) {
    pa[ct]  = pAc[(bt * 32 + n) * 128 + ct * 32 + m31];
    bia[ct] = b2[ct * 32 + m31];
  }

  f32x16 acc[4] = {};

#pragma unroll
  for (int kt = 0; kt < 8; kt++) {  // K=128 over x=(p*v) and y=|p-v| together
    V8 vf, pp, x, y;
    vf.u = *(const uint4*)&sVf[((kt * 2 + hi) * 32 + m31) * 8];
    pp.u = *(const uint4*)&sP[w * 136 + kt * 16 + hi * 8];
#pragma unroll
    for (int i = 0; i < 4; i++) {
      float vl = lo16(vf.a[i]), vh = hi16(vf.a[i]);
      float al = lo16(pp.a[i]), ah = hi16(pp.a[i]);
      x.a[i] = pk2(ah * vh, al * vl);
      y.a[i] = pk2(fabsf(ah - vh), fabsf(al - vl));
    }
    const unsigned short* bxb = w1cd + (kt * 4) * 512;
    const unsigned short* byb = w1cd + ((kt + 8) * 4) * 512;
#pragma unroll
    for (int ct = 0; ct < 4; ct++) {
      short8 bx = *(const short8*)(bxb + ct * 512 + lane * 8);
      short8 by = *(const short8*)(byb + ct * 512 + lane * 8);
      acc[ct] = __builtin_amdgcn_mfma_f32_32x32x16_bf16(x.s, bx, acc[ct], 0, 0, 0);
      acc[ct] = __builtin_amdgcn_mfma_f32_32x32x16_bf16(y.s, by, acc[ct], 0, 0, 0);
    }
  }

  // vB via indicator GEMM: A[r][k]=delta(r==k), B=vB (frag order), K=32
#pragma unroll
  for (int kt2 = 0; kt2 < 2; kt2++) {
    short8 indf;
#pragma unroll
    for (int j = 0; j < 8; j++)
      indf[j] = (short)(((kt2 * 16 + hi * 8 + j) == m31) ? 0x3F80 : 0);
#pragma unroll
    for (int ct = 0; ct < 4; ct++) {
      short8 bi = *(const short8*)(vbswt + (kt2 * 4 + ct) * 512 + lane * 8);
      acc[ct] = __builtin_amdgcn_mfma_f32_32x32x16_bf16(indf, bi, acc[ct], 0, 0, 0);
    }
  }

  // silu (pAc folded) -> 2-pass LDS transpose (32x72, per-wave) -> h@W2+b2
  unsigned short* sh = &sHt[w][0];
  f32x16 o[4] = {};
#pragma unroll
  for (int p = 0; p < 2; p++) {
#pragma unroll
    for (int c2 = 0; c2 < 2; c2++) {
      int ct = p * 2 + c2;
#pragma unroll
      for (int reg = 0; reg < 16; reg++) {
        float z = acc[ct][reg] + pa[ct];
        float hv = z * __builtin_amdgcn_rcpf(1.f + __expf(-z));
        int mr = (reg & 3) + 8 * (reg >> 2) + 4 * hi;   // C-layout row = pair m
        sh[mr * 72 + c2 * 32 + m31] = (unsigned short)(__float_as_uint(hv) >> 16);
      }
    }
#pragma unroll
    for (int kt = 0; kt < 4; kt++) {
      int ktg = p * 4 + kt;
      short8 hf = *(const short8*)&sh[m31 * 72 + kt * 16 + hi * 8];
#pragma unroll
      for (int ct2 = 0; ct2 < 4; ct2++) {
        short8 wf = *(const short8*)(w2sw + ((ktg * 4 + ct2) * 64 + lane) * 8);
        o[ct2] = __builtin_amdgcn_mfma_f32_32x32x16_bf16(hf, wf, o[ct2], 0, 0, 0);
      }
    }
  }

  int rowb = bt * 1024 + n * 32;
#pragma unroll
  for (int ct2 = 0; ct2 < 4; ct2++) {
#pragma unroll
    for (int reg = 0; reg < 16; reg++) {
      int mr = (reg & 3) + 8 * (reg >> 2) + 4 * hi;
      out[(rowb + mr) * 128 + ct2 * 32 + m31] = o[ct2][reg] + bia[ct2];
    }
  }
}

// ---------------------------------------------------------------------------
extern "C" void kernel_launch(void* const* d_in, const int* in_sizes, int n_in,
                              void* d_out, int out_size, void* d_ws, size_t ws_size,
                              hipStream_t stream) {
  const float* price  = (const float*)d_in[0];
  const float* liquid = (const float*)d_in[1];
  const float* Wp     = (const float*)d_in[2];
  const float* bp     = (const float*)d_in[3];
  const float* Wv     = (const float*)d_in[4];
  const float* bv     = (const float*)d_in[5];
  const float* W1     = (const float*)d_in[6];
  const float* b1     = (const float*)d_in[7];
  const float* W2     = (const float*)d_in[8];
  const float* b2     = (const float*)d_in[9];

  char* ws = (char*)d_ws;
  unsigned short* w1cd = (unsigned short*)(ws + 0);         //  64 KB
  unsigned short* w2sw = (unsigned short*)(ws + 65536);     //  32 KB
  unsigned short* wpsw = (unsigned short*)(ws + 98304);     //  32 KB
  unsigned short* gpsw = (unsigned short*)(ws + 131072);    //  32 KB
  unsigned short* wvsw = (unsigned short*)(ws + 163840);    //  32 KB
  unsigned short* gvsw = (unsigned short*)(ws + 196608);    //  32 KB
  float*          c1   = (float*)(ws + 229376);             // 512 B
  unsigned short* pbf  = (unsigned short*)(ws + 262144);    //   2 MB
  unsigned short* vbf  = (unsigned short*)(ws + 2359296);   //   2 MB
  float*          pAc  = (float*)(ws + 4456448);            //   4 MB
  unsigned short* vbsw = (unsigned short*)(ws + 8650752);   //   2 MB -> total ~10.3 MB

  hipLaunchKernelGGL(k0_prep, dim3(449), dim3(256), 0, stream,
                     Wp, bp, Wv, bv, W1, b1, W2, w1cd, w2sw, wpsw, gpsw, wvsw, gvsw, c1);
  hipLaunchKernelGGL(k1_proj, dim3(256), dim3(256), 0, stream,
                     price, liquid, bp, bv, c1, wpsw, gpsw, wvsw, gvsw, pbf, vbf, pAc, vbsw);
  hipLaunchKernelGGL(k2_fused, dim3(2048), dim3(256), 0, stream,
                     pbf, vbf, pAc, w1cd, vbsw, w2sw, b2, (float*)d_out);
}